// Round 17
// baseline (155.793 us; speedup 1.0000x reference)
//
#include <hip/hip_runtime.h>

// CG tensor-product iteration: per sample n, 34 (l1,l2,L) combos of
//   b[n,M,p,q] = sum_{i,j} x1_{l1}[n,i,p] * x2_{l2}[n,j,q] * C[i,j,M]
// packed into a (n, 39936) f32 row, keys (L,S) sorted, blocks concatenated.
//
// R16 WIN: nontemporal scatter stores (L2 bypass) 169 -> 148us. Remaining =
// write ~97us + VALU ~54us (4.27e9 lane-insts @ 78.6e12/s, hard floor).
// This round: halve FMA inst count via packed f32 (v_pk_fma_f32): pair the
// M-loop (M,M+1 share the ab multiplier; coefficient pairs 8B-contiguous
// after padding DL to even with zeros). Each half's chain is bit-identical
// to scalar -> absmax unchanged. Single lever on top of R16.

namespace {

typedef float f32x2 __attribute__((ext_vector_type(2)));

constexpr int NC = 34;

struct CInfo { int l1, l2, L, pbase, outbase, mstride; };
struct CTable { CInfo c[NC]; int packed_total; int outsize; };

constexpr CTable build_table() {
  CTable t{};
  // count blocks per (L, S) key; s index: 0 -> S=-1, 1 -> S=+1
  int nb[4][2] = {};
  for (int l1 = 0; l1 < 4; ++l1)
    for (int l2 = 0; l2 < 4; ++l2) {
      int lo = l1 > l2 ? l1 - l2 : l2 - l1;
      int hi = (l1 + l2 < 3) ? l1 + l2 : 3;
      for (int L = lo; L <= hi; ++L)
        nb[L][((l1 + l2 + L) & 1) ? 0 : 1]++;
    }
  // per-key offsets in sorted-key order (L asc, S=-1 before S=+1)
  int keyoff[4][2] = {};
  int off = 0;
  for (int L = 0; L < 4; ++L)
    for (int s = 0; s < 2; ++s) {
      keyoff[L][s] = off;
      off += (2 * L + 1) * 256 * nb[L][s];
    }
  t.outsize = off;
  // combos in reference iteration order; coeff runs padded to even (DL+1)
  // so M-pairs are 8B-aligned f32x2; combo bases 16-float aligned.
  int blk[4][2] = {};
  int idx = 0, pb = 0;
  for (int l1 = 0; l1 < 4; ++l1)
    for (int l2 = 0; l2 < 4; ++l2) {
      int lo = l1 > l2 ? l1 - l2 : l2 - l1;
      int hi = (l1 + l2 < 3) ? l1 + l2 : 3;
      for (int L = lo; L <= hi; ++L) {
        int s = ((l1 + l2 + L) & 1) ? 0 : 1;
        pb = (pb + 15) & ~15;
        t.c[idx].l1 = l1; t.c[idx].l2 = l2; t.c[idx].L = L;
        t.c[idx].pbase = pb;
        t.c[idx].outbase = keyoff[L][s] + blk[L][s] * 256;
        t.c[idx].mstride = 256 * nb[L][s];
        blk[L][s]++;
        pb += (2 * l1 + 1) * (2 * l2 + 1) * (2 * L + 2);  // DP2 = DL+1
        ++idx;
      }
    }
  t.packed_total = pb;
  return t;
}

constexpr CTable CTAB = build_table();
static_assert(CTAB.outsize == 39936, "output layout mismatch");
static_assert(CTAB.packed_total <= 5120, "packed cg exceeds 20KB");

// ---- coefficient pre-pack: cg[l1,l2,L,i,j,M] -> cgp[pbase + (i*D2+j)*DP2 + M]
// (pad slot M=DL zeroed so the packed pair's high half is inert).
template <int CI>
__device__ __forceinline__ void pack_combo(const float* __restrict__ cg,
                                           float* __restrict__ cgp, int tid) {
  if constexpr (CI < NC) {
    constexpr CInfo c = CTAB.c[CI];
    constexpr int D2 = 2 * c.l2 + 1, DL = 2 * c.L + 1;
    constexpr int DP2 = DL + 1;
    constexpr int SZ = (2 * c.l1 + 1) * D2 * DL;
    for (int tt = tid; tt < SZ; tt += 256) {
      int M = tt % DL, ij = tt / DL;
      int j = ij % D2, i = ij / D2;
      cgp[c.pbase + ij * DP2 + M] =
          cg[((((c.l1 * 4 + c.l2) * 4 + c.L) * 7 + i) * 7 + j) * 7 + M];
    }
    pack_combo<CI + 1>(cg, cgp, tid);
  }
}

__global__ void pack_cg_kernel(const float* __restrict__ cg,
                               float* __restrict__ cgp) {
  // zero everything first so DL..DP2 pad slots are 0
  for (int i = (int)threadIdx.x; i < CTAB.packed_total; i += 256)
    cgp[i] = 0.f;
  __syncthreads();
  pack_combo<0>(cg, cgp, (int)threadIdx.x);
}

// ---- main: one block per sample, thread = (p = tid>>4, q = tid&15).
// Packed-pair accumulation over M; nontemporal direct scatter stores.
template <int CI>
__device__ __forceinline__ void run_combos(const float* __restrict__ cgp,
                                           const float (&x1r)[16],
                                           const float (&x2r)[16],
                                           float* __restrict__ outn) {
  if constexpr (CI < NC) {
    constexpr CInfo c = CTAB.c[CI];
    constexpr int D1 = 2 * c.l1 + 1, D2 = 2 * c.l2 + 1, DL = 2 * c.L + 1;
    constexpr int DP2 = DL + 1, PR = DP2 / 2;
    constexpr int R1 = c.l1 * c.l1, R2 = c.l2 * c.l2;  // row bases: l^2
    f32x2 acc2[PR];
#pragma unroll
    for (int m = 0; m < PR; ++m) acc2[m] = f32x2{0.f, 0.f};
#pragma unroll
    for (int i = 0; i < D1; ++i) {
#pragma unroll
      for (int j = 0; j < D2; ++j) {
        const float ab = x1r[R1 + i] * x2r[R2 + j];
        const f32x2 abv = {ab, ab};
        const f32x2* cp = reinterpret_cast<const f32x2*>(
            cgp + c.pbase + (i * D2 + j) * DP2);
#pragma unroll
        for (int m = 0; m < PR; ++m)
          acc2[m] = __builtin_elementwise_fma(cp[m], abv, acc2[m]);
      }
    }
#pragma unroll
    for (int M = 0; M < DL; ++M)
      __builtin_nontemporal_store(acc2[M >> 1][M & 1],
                                  outn + c.outbase + M * c.mstride);
    run_combos<CI + 1>(cgp, x1r, x2r, outn);
  }
}

__global__ __launch_bounds__(256) void cg_main(
    const float* __restrict__ x1_0, const float* __restrict__ x2_0,
    const float* __restrict__ x1_1, const float* __restrict__ x2_1,
    const float* __restrict__ x1_2, const float* __restrict__ x2_2,
    const float* __restrict__ x1_3, const float* __restrict__ x2_3,
    const float* __restrict__ cgp_, float* __restrict__ out) {
  const float* cgp = (const float*)__builtin_assume_aligned(cgp_, 256);
  __shared__ float x1s[16][16];  // row = lm index (l^2 + i), col = Q
  __shared__ float x2s[16][16];
  const int tid = (int)threadIdx.x;
  const int n = (int)blockIdx.x;
  const int r = tid >> 4, col = tid & 15;
  // stage this sample's 2*256 input floats (each thread: 1 x1 + 1 x2 elem)
  const float* s1; const float* s2; int ri;
  if (r < 1)      { s1 = x1_0 + n * 16;  s2 = x2_0 + n * 16;  ri = r; }
  else if (r < 4) { s1 = x1_1 + n * 48;  s2 = x2_1 + n * 48;  ri = r - 1; }
  else if (r < 9) { s1 = x1_2 + n * 80;  s2 = x2_2 + n * 80;  ri = r - 4; }
  else            { s1 = x1_3 + n * 112; s2 = x2_3 + n * 112; ri = r - 9; }
  x1s[r][col] = s1[ri * 16 + col];
  x2s[r][col] = s2[ri * 16 + col];
  __syncthreads();
  // hoist this thread's columns into registers (compile-time indexed)
  float x1r[16], x2r[16];
#pragma unroll
  for (int k = 0; k < 16; ++k) {
    x1r[k] = x1s[k][r];    // p = r
    x2r[k] = x2s[k][col];  // q = col
  }
  float* outn = out + (size_t)n * (size_t)CTAB.outsize + tid;
  run_combos<0>(cgp, x1r, x2r, outn);
}

}  // namespace

extern "C" void kernel_launch(void* const* d_in, const int* in_sizes, int n_in,
                              void* d_out, int out_size, void* d_ws,
                              size_t ws_size, hipStream_t stream) {
  const float* x1[4];
  const float* x2[4];
  // setup_inputs() dict order is interleaved (x1_l0, x2_l0, x1_l1, ...);
  // detect vs grouped (x1_l0..x1_l3, x2_l0..) via sizes.
  if (in_sizes[1] == in_sizes[0]) {
    for (int l = 0; l < 4; ++l) {
      x1[l] = (const float*)d_in[2 * l];
      x2[l] = (const float*)d_in[2 * l + 1];
    }
  } else {
    for (int l = 0; l < 4; ++l) {
      x1[l] = (const float*)d_in[l];
      x2[l] = (const float*)d_in[4 + l];
    }
  }
  const float* cg = (const float*)d_in[8];
  float* out = (float*)d_out;
  float* cgp = (float*)d_ws;  // packed coefficients (~20 KB padded)

  const int n = in_sizes[0] / 16;  // x?_l0 is (n, 1, 16)

  pack_cg_kernel<<<1, 256, 0, stream>>>(cg, cgp);
  cg_main<<<n, 256, 0, stream>>>(x1[0], x2[0], x1[1], x2[1], x1[2], x2[2],
                                 x1[3], x2[3], cgp, out);
}

// Round 18
// 154.214 us; speedup vs baseline: 1.0102x; 1.0102x over previous
//
#include <hip/hip_runtime.h>

// CG tensor-product iteration: per sample n, 34 (l1,l2,L) combos of
//   b[n,M,p,q] = sum_{i,j} x1_{l1}[n,i,p] * x2_{l2}[n,j,q] * C[i,j,M]
// packed into a (n, 39936) f32 row, keys (L,S) sorted, blocks concatenated.
//
// R16 WIN: nt scatter stores 169 -> 148us. R17 pk-FMA regressed (156).
// Two models both predict R16=148: (a) additive VALU+write, (b) pure
// store floor with 1KB-scatter nt efficiency ~65%. They diverge on
// linear-span nt writes: (a) ~143us, (b) ~105-120us. This round decides:
// R11 verbatim (half-row staging, 512thr, 2 blocks/CU, linear 28-51KB
// span flush, proven 163.9/abs 0.125) with the flush stores made
// nontemporal. Single instruction lever.

namespace {

typedef float f32x4 __attribute__((ext_vector_type(4)));

constexpr int NC = 34;
constexpr int NKEY = 8;

struct CInfo { int l1, l2, L, key, pbase, blk, nbc, half, grp, lbase; };
struct Span { int gbase, lbase, nf; };       // floats
struct HInfo { int segf; Span sp[2]; };
struct Tables {
  CInfo c[NC];
  HInfo h[2];
  int packed_total;
  int outsize;
};

constexpr int halfof(int key) { return (key == 5 || key == 7) ? 1 : 0; }

constexpr Tables build() {
  Tables t{};
  // key index k = L*2 + s, s: 0 -> S=-1, 1 -> S=+1 (sorted key order)
  int nb[NKEY] = {};
  for (int l1 = 0; l1 < 4; ++l1)
    for (int l2 = 0; l2 < 4; ++l2) {
      int lo = l1 > l2 ? l1 - l2 : l2 - l1;
      int hi = (l1 + l2 < 3) ? l1 + l2 : 3;
      for (int L = lo; L <= hi; ++L)
        nb[L * 2 + (((l1 + l2 + L) & 1) ? 0 : 1)]++;
    }
  int keyf[NKEY] = {}, keyoff[NKEY] = {};
  int off = 0;
  for (int k = 0; k < NKEY; ++k) {
    keyf[k] = (2 * (k >> 1) + 1) * 256 * nb[k];
    keyoff[k] = off;
    off += keyf[k];
  }
  t.outsize = off;
  // local (per-half LDS) bases
  int lbase[NKEY] = {};
  {
    int o0 = 0, o1 = 0;
    for (int k = 0; k < NKEY; ++k) {
      if (keyf[k] == 0) { lbase[k] = 0; continue; }
      if (halfof(k) == 0) { lbase[k] = o0; o0 += keyf[k]; }
      else                { lbase[k] = o1; o1 += keyf[k]; }
    }
    t.h[0].segf = o0;
    t.h[1].segf = o1;
  }
  // flush spans: half0 = [keys1..4 contiguous] + [key6]; half1 = [key5]+[key7]
  t.h[0].sp[0] = Span{keyoff[1], lbase[1],
                      keyf[1] + keyf[2] + keyf[3] + keyf[4]};
  t.h[0].sp[1] = Span{keyoff[6], lbase[6], keyf[6]};
  t.h[1].sp[0] = Span{keyoff[5], lbase[5], keyf[5]};
  t.h[1].sp[1] = Span{keyoff[7], lbase[7], keyf[7]};
  // combos in reference iteration order; greedy 2-group balance per half
  int blk[NKEY] = {};
  int gcost[2][2] = {};
  int idx = 0, pb = 0;
  for (int l1 = 0; l1 < 4; ++l1)
    for (int l2 = 0; l2 < 4; ++l2) {
      int lo = l1 > l2 ? l1 - l2 : l2 - l1;
      int hi = (l1 + l2 < 3) ? l1 + l2 : 3;
      for (int L = lo; L <= hi; ++L) {
        int s = ((l1 + l2 + L) & 1) ? 0 : 1;
        int k = L * 2 + s;
        pb = (pb + 15) & ~15;
        int h = halfof(k);
        int cost = (2 * l1 + 1) * (2 * l2 + 1) * (2 * L + 1);
        int g = (gcost[h][0] <= gcost[h][1]) ? 0 : 1;
        gcost[h][g] += cost;
        t.c[idx].l1 = l1; t.c[idx].l2 = l2; t.c[idx].L = L;
        t.c[idx].key = k;
        t.c[idx].pbase = pb;
        t.c[idx].blk = blk[k];
        t.c[idx].nbc = nb[k] * 256;
        t.c[idx].half = h;
        t.c[idx].grp = g;
        t.c[idx].lbase = lbase[k];
        blk[k]++;
        pb += cost;
        ++idx;
      }
    }
  t.packed_total = pb;
  return t;
}

constexpr Tables TAB = build();
static_assert(TAB.outsize == 39936, "output layout mismatch");
static_assert(TAB.packed_total <= 4096, "packed cg exceeds 16KB");
static_assert(TAB.h[0].segf == 20224, "half A should be 79KB");
static_assert(TAB.h[1].segf == 19712, "half B should be 77KB");

// ---- coefficient pre-pack: gather cg[l1,l2,L,i,j,M] into contiguous,
// combo-major, (i,j,M)-ordered table in workspace (read order of main loop).
template <int CI>
__device__ __forceinline__ void pack_combo(const float* __restrict__ cg,
                                           float* __restrict__ cgp, int tid) {
  if constexpr (CI < NC) {
    constexpr CInfo c = TAB.c[CI];
    constexpr int D2 = 2 * c.l2 + 1, DL = 2 * c.L + 1;
    constexpr int SZ = (2 * c.l1 + 1) * D2 * DL;
    for (int tt = tid; tt < SZ; tt += 256) {
      int M = tt % DL, ij = tt / DL;
      int j = ij % D2, i = ij / D2;
      cgp[c.pbase + tt] =
          cg[((((c.l1 * 4 + c.l2) * 4 + c.L) * 7 + i) * 7 + j) * 7 + M];
    }
    pack_combo<CI + 1>(cg, cgp, tid);
  }
}

__global__ void pack_cg_kernel(const float* __restrict__ cg,
                               float* __restrict__ cgp) {
  pack_combo<0>(cg, cgp, (int)threadIdx.x);
}

// ---- group compute: 256-thread group runs its combos; t = tid&255 ->
// (p = t>>4, q = t&15); stage at seg[lbase + M*nbc + blk*256 + t].
template <int HALF, int GRP, int CI>
__device__ __forceinline__ void grp_combos(const float* __restrict__ cgp,
                                           const float (&x1r)[16],
                                           const float (&x2r)[16],
                                           float* __restrict__ seg, int t) {
  if constexpr (CI < NC) {
    constexpr CInfo c = TAB.c[CI];
    if constexpr (c.half == HALF && c.grp == GRP) {
      constexpr int D1 = 2 * c.l1 + 1, D2 = 2 * c.l2 + 1, DL = 2 * c.L + 1;
      constexpr int R1 = c.l1 * c.l1, R2 = c.l2 * c.l2;  // row bases: l^2
      float acc[DL];
#pragma unroll
      for (int M = 0; M < DL; ++M) acc[M] = 0.f;
#pragma unroll
      for (int i = 0; i < D1; ++i) {
#pragma unroll
        for (int j = 0; j < D2; ++j) {
          const float ab = x1r[R1 + i] * x2r[R2 + j];
#pragma unroll
          for (int M = 0; M < DL; ++M)
            acc[M] = fmaf(cgp[c.pbase + (i * D2 + j) * DL + M], ab, acc[M]);
        }
      }
#pragma unroll
      for (int M = 0; M < DL; ++M)
        seg[c.lbase + M * c.nbc + c.blk * 256 + t] = acc[M];
    }
    grp_combos<HALF, GRP, CI + 1>(cgp, x1r, x2r, seg, t);
  }
}

// ---- flush: 2 linear spans, 512 threads, nontemporal f32x4 each.
template <int HALF>
__device__ __forceinline__ void flush_half(const float* __restrict__ seg,
                                           float* __restrict__ outrow,
                                           int tid) {
#pragma unroll
  for (int si = 0; si < 2; ++si) {
    const Span S = TAB.h[HALF].sp[si];
    const int NF4 = S.nf / 4;
    const f32x4* sb = reinterpret_cast<const f32x4*>(seg + S.lbase);
    f32x4* ob = reinterpret_cast<f32x4*>(outrow + S.gbase);
#pragma unroll
    for (int k = 0; k < (NF4 + 511) / 512; ++k) {
      const int idx = tid + 512 * k;
      if (idx < NF4) __builtin_nontemporal_store(sb[idx], ob + idx);
    }
  }
}

// ---- main: block = (sample, half). 512 threads = 2 combo-groups.
__global__ __launch_bounds__(512) void cg_main(
    const float* __restrict__ x1_0, const float* __restrict__ x2_0,
    const float* __restrict__ x1_1, const float* __restrict__ x2_1,
    const float* __restrict__ x1_2, const float* __restrict__ x2_2,
    const float* __restrict__ x1_3, const float* __restrict__ x2_3,
    const float* __restrict__ cgp_, float* __restrict__ out) {
  const float* cgp = (const float*)__builtin_assume_aligned(cgp_, 256);
  __shared__ __align__(16) float seg[20224];  // 79KB: half-row staging
  const int tid = (int)threadIdx.x;
  const int id = (int)blockIdx.x;
  const int n = id >> 1, half = id & 1;
  const int t = tid & 255;
  const int r = t >> 4, col = t & 15;
  // stage this sample's 2*256 input floats into seg[0:512] (scratch):
  // tid<256 loads x1 element (r,col), tid>=256 loads x2 element.
  {
    const float* s1; const float* s2; int ri;
    if (r < 1)      { s1 = x1_0 + n * 16;  s2 = x2_0 + n * 16;  ri = r; }
    else if (r < 4) { s1 = x1_1 + n * 48;  s2 = x2_1 + n * 48;  ri = r - 1; }
    else if (r < 9) { s1 = x1_2 + n * 80;  s2 = x2_2 + n * 80;  ri = r - 4; }
    else            { s1 = x1_3 + n * 112; s2 = x2_3 + n * 112; ri = r - 9; }
    if (tid < 256) seg[t] = s1[ri * 16 + col];
    else           seg[256 + t] = s2[ri * 16 + col];
  }
  __syncthreads();
  // hoist this thread's columns into registers (compile-time indexed)
  float x1r[16], x2r[16];
#pragma unroll
  for (int k = 0; k < 16; ++k) {
    x1r[k] = seg[k * 16 + r];          // p = r
    x2r[k] = seg[256 + k * 16 + col];  // q = col
  }
  __syncthreads();  // seg[0:512] dead; compute may overwrite it
  const int grp = tid >> 8;
  if (half == 0) {
    if (grp == 0) grp_combos<0, 0, 0>(cgp, x1r, x2r, seg, t);
    else          grp_combos<0, 1, 0>(cgp, x1r, x2r, seg, t);
  } else {
    if (grp == 0) grp_combos<1, 0, 0>(cgp, x1r, x2r, seg, t);
    else          grp_combos<1, 1, 0>(cgp, x1r, x2r, seg, t);
  }
  __syncthreads();
  float* outrow = out + (size_t)n * (size_t)TAB.outsize;
  if (half == 0) flush_half<0>(seg, outrow, tid);
  else           flush_half<1>(seg, outrow, tid);
}

}  // namespace

extern "C" void kernel_launch(void* const* d_in, const int* in_sizes, int n_in,
                              void* d_out, int out_size, void* d_ws,
                              size_t ws_size, hipStream_t stream) {
  const float* x1[4];
  const float* x2[4];
  // setup_inputs() dict order is interleaved (x1_l0, x2_l0, x1_l1, ...);
  // detect vs grouped (x1_l0..x1_l3, x2_l0..) via sizes.
  if (in_sizes[1] == in_sizes[0]) {
    for (int l = 0; l < 4; ++l) {
      x1[l] = (const float*)d_in[2 * l];
      x2[l] = (const float*)d_in[2 * l + 1];
    }
  } else {
    for (int l = 0; l < 4; ++l) {
      x1[l] = (const float*)d_in[l];
      x2[l] = (const float*)d_in[4 + l];
    }
  }
  const float* cg = (const float*)d_in[8];
  float* out = (float*)d_out;
  float* cgp = (float*)d_ws;  // packed coefficients (~16 KB)

  const int n = in_sizes[0] / 16;  // x?_l0 is (n, 1, 16)

  pack_cg_kernel<<<1, 256, 0, stream>>>(cg, cgp);
  cg_main<<<2 * n, 512, 0, stream>>>(x1[0], x2[0], x1[1], x2[1], x1[2],
                                     x2[2], x1[3], x2[3], cgp, out);
}

// Round 19
// 152.302 us; speedup vs baseline: 1.0229x; 1.0126x over previous
//
#include <hip/hip_runtime.h>

// CG tensor-product iteration: per sample n, 34 (l1,l2,L) combos of
//   b[n,M,p,q] = sum_{i,j} x1_{l1}[n,i,p] * x2_{l2}[n,j,q] * C[i,j,M]
// packed into a (n, 39936) f32 row, keys (L,S) sorted, blocks concatenated.
//
// R16 (nt 256B-chunk scatter): 148us = ~97us write floor + ~51us VALU
// residue; effective nt-scatter write ~4.4 TB/s vs fill 6.6. Last variable:
// wave-chunk size. This round: R3's staged structure (166us, 16KB LDS,
// ~8 blocks/CU, 1KB contiguous float4 wave-chunks) with (1) nt flush
// stores and (2) per-combo barrier = lgkmcnt-only (s_barrier without
// vmcnt drain) so nt stores free-run across combos.

namespace {

typedef float f32x4 __attribute__((ext_vector_type(4)));

constexpr int NC = 34;

struct CInfo { int l1, l2, L, pbase, outbase, mstride; };
struct CTable { CInfo c[NC]; int packed_total; int outsize; };

constexpr CTable build_table() {
  CTable t{};
  // count blocks per (L, S) key; s index: 0 -> S=-1, 1 -> S=+1
  int nb[4][2] = {};
  for (int l1 = 0; l1 < 4; ++l1)
    for (int l2 = 0; l2 < 4; ++l2) {
      int lo = l1 > l2 ? l1 - l2 : l2 - l1;
      int hi = (l1 + l2 < 3) ? l1 + l2 : 3;
      for (int L = lo; L <= hi; ++L)
        nb[L][((l1 + l2 + L) & 1) ? 0 : 1]++;
    }
  // per-key offsets in sorted-key order (L asc, S=-1 before S=+1)
  int keyoff[4][2] = {};
  int off = 0;
  for (int L = 0; L < 4; ++L)
    for (int s = 0; s < 2; ++s) {
      keyoff[L][s] = off;
      off += (2 * L + 1) * 256 * nb[L][s];
    }
  t.outsize = off;
  // combos in reference iteration order; packed-coeff bases 16-aligned
  int blk[4][2] = {};
  int idx = 0, pb = 0;
  for (int l1 = 0; l1 < 4; ++l1)
    for (int l2 = 0; l2 < 4; ++l2) {
      int lo = l1 > l2 ? l1 - l2 : l2 - l1;
      int hi = (l1 + l2 < 3) ? l1 + l2 : 3;
      for (int L = lo; L <= hi; ++L) {
        int s = ((l1 + l2 + L) & 1) ? 0 : 1;
        pb = (pb + 15) & ~15;
        t.c[idx].l1 = l1; t.c[idx].l2 = l2; t.c[idx].L = L;
        t.c[idx].pbase = pb;
        t.c[idx].outbase = keyoff[L][s] + blk[L][s] * 256;
        t.c[idx].mstride = 256 * nb[L][s];
        blk[L][s]++;
        pb += (2 * l1 + 1) * (2 * l2 + 1) * (2 * L + 1);
        ++idx;
      }
    }
  t.packed_total = pb;
  return t;
}

constexpr CTable CTAB = build_table();
static_assert(CTAB.outsize == 39936, "output layout mismatch");
static_assert(CTAB.packed_total <= 4096, "packed cg exceeds 16KB");

// ---- coefficient pre-pack: gather cg[l1,l2,L,i,j,M] into contiguous,
// combo-major, (i,j,M)-ordered table in workspace (read order of main loop).
template <int CI>
__device__ __forceinline__ void pack_combo(const float* __restrict__ cg,
                                           float* __restrict__ cgp, int tid) {
  if constexpr (CI < NC) {
    constexpr CInfo c = CTAB.c[CI];
    constexpr int D2 = 2 * c.l2 + 1, DL = 2 * c.L + 1;
    constexpr int SZ = (2 * c.l1 + 1) * D2 * DL;
    for (int tt = tid; tt < SZ; tt += 256) {
      int M = tt % DL, ij = tt / DL;
      int j = ij % D2, i = ij / D2;
      cgp[c.pbase + tt] =
          cg[((((c.l1 * 4 + c.l2) * 4 + c.L) * 7 + i) * 7 + j) * 7 + M];
    }
    pack_combo<CI + 1>(cg, cgp, tid);
  }
}

__global__ void pack_cg_kernel(const float* __restrict__ cg,
                               float* __restrict__ cgp) {
  pack_combo<0>(cg, cgp, (int)threadIdx.x);
}

// Barrier that drains LDS ops only: nt global stores remain in flight
// (__syncthreads would emit s_waitcnt vmcnt(0) and stall on HBM acks).
__device__ __forceinline__ void lds_barrier() {
  __builtin_amdgcn_sched_barrier(0);
  asm volatile("s_waitcnt lgkmcnt(0)" ::: "memory");
  __builtin_amdgcn_s_barrier();
  __builtin_amdgcn_sched_barrier(0);
}

// ---- main: one block per sample, thread = (p = tid>>4, q = tid&15).
// Scalar accumulation (low VGPR); per-combo LDS stage + nt float4 flush
// (1KB contiguous per wave-inst); lgkm-only barrier between combos.
template <int CI>
__device__ __forceinline__ void run_combos(const float* __restrict__ cgp,
                                           const float (&x1r)[16],
                                           const float (&x2r)[16],
                                           float* __restrict__ stage,
                                           float* __restrict__ outn,
                                           int tid) {
  if constexpr (CI < NC) {
    constexpr CInfo c = CTAB.c[CI];
    constexpr int D1 = 2 * c.l1 + 1, D2 = 2 * c.l2 + 1, DL = 2 * c.L + 1;
    constexpr int R1 = c.l1 * c.l1, R2 = c.l2 * c.l2;  // row bases: l^2
    float acc[DL];
#pragma unroll
    for (int M = 0; M < DL; ++M) acc[M] = 0.f;
#pragma unroll
    for (int i = 0; i < D1; ++i) {
#pragma unroll
      for (int j = 0; j < D2; ++j) {
        const float ab = x1r[R1 + i] * x2r[R2 + j];
#pragma unroll
        for (int M = 0; M < DL; ++M)
          acc[M] = fmaf(cgp[c.pbase + (i * D2 + j) * DL + M], ab, acc[M]);
      }
    }
    // stage scalar results (conflict-free ds_write_b32), then flush as
    // nt float4: wave w writes row M = w + 4k (1KB contiguous per inst).
    float* buf = stage + (CI & 1) * 1792;
#pragma unroll
    for (int M = 0; M < DL; ++M) buf[M * 256 + tid] = acc[M];
    lds_barrier();
    const unsigned w = (unsigned)tid >> 6, l = (unsigned)tid & 63u;
#pragma unroll
    for (int k = 0; k < (DL + 3) / 4; ++k) {
      const unsigned M = w + 4u * k;
      if (M < (unsigned)DL) {
        const f32x4 v = *reinterpret_cast<const f32x4*>(buf + M * 256 + 4 * l);
        __builtin_nontemporal_store(
            v, reinterpret_cast<f32x4*>(outn + c.outbase + M * c.mstride +
                                        4 * l));
      }
    }
    // no second barrier: next combo uses the other stage buffer, whose last
    // readers (flush ds_reads of combo CI-1) completed at this barrier.
    run_combos<CI + 1>(cgp, x1r, x2r, stage, outn, tid);
  }
}

__global__ __launch_bounds__(256) void cg_main(
    const float* __restrict__ x1_0, const float* __restrict__ x2_0,
    const float* __restrict__ x1_1, const float* __restrict__ x2_1,
    const float* __restrict__ x1_2, const float* __restrict__ x2_2,
    const float* __restrict__ x1_3, const float* __restrict__ x2_3,
    const float* __restrict__ cgp_, float* __restrict__ out) {
  const float* cgp = (const float*)__builtin_assume_aligned(cgp_, 256);
  __shared__ float x1s[16][16];  // row = lm index (l^2 + i), col = Q
  __shared__ float x2s[16][16];
  __shared__ __align__(16) float stage[2 * 1792];  // double-buffered flush
  const int tid = (int)threadIdx.x;
  const int n = (int)blockIdx.x;
  const int r = tid >> 4, col = tid & 15;
  // stage this sample's 2*256 input floats (each thread: 1 x1 + 1 x2 elem)
  const float* s1; const float* s2; int ri;
  if (r < 1)      { s1 = x1_0 + n * 16;  s2 = x2_0 + n * 16;  ri = r; }
  else if (r < 4) { s1 = x1_1 + n * 48;  s2 = x2_1 + n * 48;  ri = r - 1; }
  else if (r < 9) { s1 = x1_2 + n * 80;  s2 = x2_2 + n * 80;  ri = r - 4; }
  else            { s1 = x1_3 + n * 112; s2 = x2_3 + n * 112; ri = r - 9; }
  x1s[r][col] = s1[ri * 16 + col];
  x2s[r][col] = s2[ri * 16 + col];
  __syncthreads();
  // hoist this thread's columns into registers (compile-time indexed)
  float x1r[16], x2r[16];
#pragma unroll
  for (int k = 0; k < 16; ++k) {
    x1r[k] = x1s[k][r];    // p = r
    x2r[k] = x2s[k][col];  // q = col
  }
  float* outn = out + (size_t)n * (size_t)CTAB.outsize;
  run_combos<0>(cgp, x1r, x2r, stage, outn, tid);
}

}  // namespace

extern "C" void kernel_launch(void* const* d_in, const int* in_sizes, int n_in,
                              void* d_out, int out_size, void* d_ws,
                              size_t ws_size, hipStream_t stream) {
  const float* x1[4];
  const float* x2[4];
  // setup_inputs() dict order is interleaved (x1_l0, x2_l0, x1_l1, ...);
  // detect vs grouped (x1_l0..x1_l3, x2_l0..) via sizes.
  if (in_sizes[1] == in_sizes[0]) {
    for (int l = 0; l < 4; ++l) {
      x1[l] = (const float*)d_in[2 * l];
      x2[l] = (const float*)d_in[2 * l + 1];
    }
  } else {
    for (int l = 0; l < 4; ++l) {
      x1[l] = (const float*)d_in[l];
      x2[l] = (const float*)d_in[4 + l];
    }
  }
  const float* cg = (const float*)d_in[8];
  float* out = (float*)d_out;
  float* cgp = (float*)d_ws;  // packed coefficients (~16 KB)

  const int n = in_sizes[0] / 16;  // x?_l0 is (n, 1, 16)

  pack_cg_kernel<<<1, 256, 0, stream>>>(cg, cgp);
  cg_main<<<n, 256, 0, stream>>>(x1[0], x2[0], x1[1], x2[1], x1[2], x2[2],
                                 x1[3], x2[3], cgp, out);
}

// Round 20
// 148.100 us; speedup vs baseline: 1.0519x; 1.0284x over previous
//
#include <hip/hip_runtime.h>

// CG tensor-product iteration: per sample n, 34 (l1,l2,L) combos of
//   b[n,M,p,q] = sum_{i,j} x1_{l1}[n,i,p] * x2_{l2}[n,j,q] * C[i,j,M]
// packed into a (n, 39936) f32 row, keys (L,S) sorted, blocks concatenated.
//
// FINAL (R16 structure, best of 19 rounds: 148.2us):
// one block/sample, LDS input staging, scalar accumulation, NONTEMPORAL
// direct scatter stores (L2 bypass was the one real win: 169 -> 148).
// Falsified levers: store width/pattern/chunk-size, coeff path, FMA-count
// reduction (LDS trade), pk-FMA, phase desync, linear write fronts.
// Wall = HBM write floor (~97us) + partially-hidden VALU (~50us).

namespace {

constexpr int NC = 34;

struct CInfo { int l1, l2, L, pbase, outbase, mstride; };
struct CTable { CInfo c[NC]; int packed_total; int outsize; };

constexpr CTable build_table() {
  CTable t{};
  // count blocks per (L, S) key; s index: 0 -> S=-1, 1 -> S=+1
  int nb[4][2] = {};
  for (int l1 = 0; l1 < 4; ++l1)
    for (int l2 = 0; l2 < 4; ++l2) {
      int lo = l1 > l2 ? l1 - l2 : l2 - l1;
      int hi = (l1 + l2 < 3) ? l1 + l2 : 3;
      for (int L = lo; L <= hi; ++L)
        nb[L][((l1 + l2 + L) & 1) ? 0 : 1]++;
    }
  // per-key offsets in sorted-key order (L asc, S=-1 before S=+1)
  int keyoff[4][2] = {};
  int off = 0;
  for (int L = 0; L < 4; ++L)
    for (int s = 0; s < 2; ++s) {
      keyoff[L][s] = off;
      off += (2 * L + 1) * 256 * nb[L][s];
    }
  t.outsize = off;
  // combos in reference iteration order; packed-coeff bases 16-aligned
  int blk[4][2] = {};
  int idx = 0, pb = 0;
  for (int l1 = 0; l1 < 4; ++l1)
    for (int l2 = 0; l2 < 4; ++l2) {
      int lo = l1 > l2 ? l1 - l2 : l2 - l1;
      int hi = (l1 + l2 < 3) ? l1 + l2 : 3;
      for (int L = lo; L <= hi; ++L) {
        int s = ((l1 + l2 + L) & 1) ? 0 : 1;
        pb = (pb + 15) & ~15;
        t.c[idx].l1 = l1; t.c[idx].l2 = l2; t.c[idx].L = L;
        t.c[idx].pbase = pb;
        t.c[idx].outbase = keyoff[L][s] + blk[L][s] * 256;
        t.c[idx].mstride = 256 * nb[L][s];
        blk[L][s]++;
        pb += (2 * l1 + 1) * (2 * l2 + 1) * (2 * L + 1);
        ++idx;
      }
    }
  t.packed_total = pb;
  return t;
}

constexpr CTable CTAB = build_table();
static_assert(CTAB.outsize == 39936, "output layout mismatch");
static_assert(CTAB.packed_total <= 4096, "packed cg exceeds 16KB");

// ---- coefficient pre-pack: gather cg[l1,l2,L,i,j,M] into contiguous,
// combo-major, (i,j,M)-ordered table in workspace (read order of main loop).
template <int CI>
__device__ __forceinline__ void pack_combo(const float* __restrict__ cg,
                                           float* __restrict__ cgp, int tid) {
  if constexpr (CI < NC) {
    constexpr CInfo c = CTAB.c[CI];
    constexpr int D2 = 2 * c.l2 + 1, DL = 2 * c.L + 1;
    constexpr int SZ = (2 * c.l1 + 1) * D2 * DL;
    for (int tt = tid; tt < SZ; tt += 256) {
      int M = tt % DL, ij = tt / DL;
      int j = ij % D2, i = ij / D2;
      cgp[c.pbase + tt] =
          cg[((((c.l1 * 4 + c.l2) * 4 + c.L) * 7 + i) * 7 + j) * 7 + M];
    }
    pack_combo<CI + 1>(cg, cgp, tid);
  }
}

__global__ void pack_cg_kernel(const float* __restrict__ cg,
                               float* __restrict__ cgp) {
  pack_combo<0>(cg, cgp, (int)threadIdx.x);
}

// ---- main: one block per sample, thread = (p = tid>>4, q = tid&15).
// Scalar accumulation; nontemporal direct scatter stores (L2 bypass).
template <int CI>
__device__ __forceinline__ void run_combos(const float* __restrict__ cgp,
                                           const float (&x1r)[16],
                                           const float (&x2r)[16],
                                           float* __restrict__ outn) {
  if constexpr (CI < NC) {
    constexpr CInfo c = CTAB.c[CI];
    constexpr int D1 = 2 * c.l1 + 1, D2 = 2 * c.l2 + 1, DL = 2 * c.L + 1;
    constexpr int R1 = c.l1 * c.l1, R2 = c.l2 * c.l2;  // row bases: l^2
    float acc[DL];
#pragma unroll
    for (int M = 0; M < DL; ++M) acc[M] = 0.f;
#pragma unroll
    for (int i = 0; i < D1; ++i) {
#pragma unroll
      for (int j = 0; j < D2; ++j) {
        const float ab = x1r[R1 + i] * x2r[R2 + j];
#pragma unroll
        for (int M = 0; M < DL; ++M)
          acc[M] = fmaf(cgp[c.pbase + (i * D2 + j) * DL + M], ab, acc[M]);
      }
    }
#pragma unroll
    for (int M = 0; M < DL; ++M)
      __builtin_nontemporal_store(acc[M], outn + c.outbase + M * c.mstride);
    run_combos<CI + 1>(cgp, x1r, x2r, outn);
  }
}

__global__ __launch_bounds__(256) void cg_main(
    const float* __restrict__ x1_0, const float* __restrict__ x2_0,
    const float* __restrict__ x1_1, const float* __restrict__ x2_1,
    const float* __restrict__ x1_2, const float* __restrict__ x2_2,
    const float* __restrict__ x1_3, const float* __restrict__ x2_3,
    const float* __restrict__ cgp_, float* __restrict__ out) {
  const float* cgp = (const float*)__builtin_assume_aligned(cgp_, 256);
  __shared__ float x1s[16][16];  // row = lm index (l^2 + i), col = Q
  __shared__ float x2s[16][16];
  const int tid = (int)threadIdx.x;
  const int n = (int)blockIdx.x;
  const int r = tid >> 4, col = tid & 15;
  // stage this sample's 2*256 input floats (each thread: 1 x1 + 1 x2 elem)
  const float* s1; const float* s2; int ri;
  if (r < 1)      { s1 = x1_0 + n * 16;  s2 = x2_0 + n * 16;  ri = r; }
  else if (r < 4) { s1 = x1_1 + n * 48;  s2 = x2_1 + n * 48;  ri = r - 1; }
  else if (r < 9) { s1 = x1_2 + n * 80;  s2 = x2_2 + n * 80;  ri = r - 4; }
  else            { s1 = x1_3 + n * 112; s2 = x2_3 + n * 112; ri = r - 9; }
  x1s[r][col] = s1[ri * 16 + col];
  x2s[r][col] = s2[ri * 16 + col];
  __syncthreads();
  // hoist this thread's columns into registers (compile-time indexed)
  float x1r[16], x2r[16];
#pragma unroll
  for (int k = 0; k < 16; ++k) {
    x1r[k] = x1s[k][r];    // p = r
    x2r[k] = x2s[k][col];  // q = col
  }
  float* outn = out + (size_t)n * (size_t)CTAB.outsize + tid;
  run_combos<0>(cgp, x1r, x2r, outn);
}

}  // namespace

extern "C" void kernel_launch(void* const* d_in, const int* in_sizes, int n_in,
                              void* d_out, int out_size, void* d_ws,
                              size_t ws_size, hipStream_t stream) {
  const float* x1[4];
  const float* x2[4];
  // setup_inputs() dict order is interleaved (x1_l0, x2_l0, x1_l1, ...);
  // detect vs grouped (x1_l0..x1_l3, x2_l0..) via sizes.
  if (in_sizes[1] == in_sizes[0]) {
    for (int l = 0; l < 4; ++l) {
      x1[l] = (const float*)d_in[2 * l];
      x2[l] = (const float*)d_in[2 * l + 1];
    }
  } else {
    for (int l = 0; l < 4; ++l) {
      x1[l] = (const float*)d_in[l];
      x2[l] = (const float*)d_in[4 + l];
    }
  }
  const float* cg = (const float*)d_in[8];
  float* out = (float*)d_out;
  float* cgp = (float*)d_ws;  // packed coefficients (~16 KB)

  const int n = in_sizes[0] / 16;  // x?_l0 is (n, 1, 16)

  pack_cg_kernel<<<1, 256, 0, stream>>>(cg, cgp);
  cg_main<<<n, 256, 0, stream>>>(x1[0], x2[0], x1[1], x2[1], x1[2], x2[2],
                                 x1[3], x2[3], cgp, out);
}